// Round 15
// baseline (317.690 us; speedup 1.0000x reference)
//
#include <hip/hip_runtime.h>
#include <hip/hip_bf16.h>
#include <stdint.h>

typedef __bf16 bf16;
typedef __bf16 bf16x8 __attribute__((ext_vector_type(8)));
typedef __bf16 bf16x4 __attribute__((ext_vector_type(4)));
typedef float floatx4 __attribute__((ext_vector_type(4)));

#define NSEQ   1024
#define DM     2048
#define NH     16
#define DHD    128
#define E3     6144
#define SCALE_F 0.08838834764831845f
#define MBIAS_S (-1.0e9f * SCALE_F)
#define NEG_HUGE (-3.0e38f)
#define DEFER_THR 8.0f

static __device__ __forceinline__ floatx4 mfma16(bf16x8 a, bf16x8 b, floatx4 c) {
  return __builtin_amdgcn_mfma_f32_16x16x32_bf16(a, b, c, 0, 0, 0);
}

// global -> LDS direct copy, 16B per lane. LDS dest is wave-uniform base;
// HW adds lane*16.
static __device__ __forceinline__ void load_lds16(const bf16* g, bf16* l) {
  __builtin_amdgcn_global_load_lds(
      (__attribute__((address_space(1))) const void*)g,
      (__attribute__((address_space(3))) void*)l, 16, 0, 0);
}

#define SCHED0 __builtin_amdgcn_sched_barrier(0)

// ------- fused cast f32 -> bf16 for x, w_in, w_out (one dispatch) ---------
__global__ __launch_bounds__(256) void cast3_kernel(
    const float* __restrict__ x, const float* __restrict__ wi,
    const float* __restrict__ wo, bf16* __restrict__ xb,
    bf16* __restrict__ wib, bf16* __restrict__ wob) {
  const int blk = blockIdx.x;
  const float* src;
  bf16* dst;
  int base;
  if (blk < 8192)       { src = x;  dst = xb;  base = blk; }
  else if (blk < 20480) { src = wi; dst = wib; base = blk - 8192; }
  else                  { src = wo; dst = wob; base = blk - 20480; }
  const int i = base * 256 + threadIdx.x;
  float4 v = ((const float4*)src)[i];
  bf16x4 o;
  o[0] = (bf16)v.x; o[1] = (bf16)v.y; o[2] = (bf16)v.z; o[3] = (bf16)v.w;
  ((bf16x4*)dst)[i] = o;
}

// ======== 256x256 GEMM, 2 merged phases per K-tile (32 MFMA/region) =======
// C[M,N] = A[M,K]*B[N,K]^T (+bias). 512 thr = 8 waves (2M x 4N), BK=64 in
// two kh slots; LDS [2][2][256][32], colpair^=(row>>1)&3 swizzle. Counted
// vmcnt(8); never vmcnt(0) in loop. NO blockIdx chunking (r13: chunking
// doubled FETCH). Fused V-transpose epilogue (r14 verified: -8 us): for
// tn >= 16 write vt[b,h,dh,s] directly (acc fragment holds 4 consecutive
// s -> bf16x4 store), skip the dead qkv V-region C-write.
template <typename OutT>
__global__ __launch_bounds__(512) void gemm256_bt_kernel(
    const bf16* __restrict__ A, const bf16* __restrict__ B,
    OutT* __restrict__ C, const float* __restrict__ bias,
    int N, int K, bf16* __restrict__ vt) {
  __shared__ __align__(16) bf16 Al[2][2][256 * 32];
  __shared__ __align__(16) bf16 Bl[2][2][256 * 32];
  const int NT = K >> 6;
  const int ntn = N >> 8;
  const int tm = blockIdx.x / ntn;
  const int tn = blockIdx.x - tm * ntn;
  const int tid = threadIdx.x;
  const int w = tid >> 6, lane = tid & 63;
  const int lq = lane & 15, lg = lane >> 4;
  const int wr = w >> 2, wc = w & 3;
  const int sub = lane >> 2;                       // staging row-in-chunk
  const int cpl = (lane & 3) ^ ((lane >> 3) & 3);  // pre-swizzled src colpair
  const int scp8 = (lg ^ ((lq >> 1) & 3)) << 3;    // swizzled read col (elems)

  const bf16* Ag = A + (size_t)(tm * 256) * K;
  const bf16* Bg = B + (size_t)(tn * 256) * K;

  auto STAGE = [&](const bf16* G, bf16* Ldst, int kcol) {
#pragma unroll
    for (int j = 0; j < 2; j++) {
      const int r0 = w * 32 + j * 16;
      load_lds16(G + (size_t)(r0 + sub) * K + kcol + cpl * 8, Ldst + r0 * 32);
    }
  };
  auto RD = [&](const bf16* slot, int rbase) -> bf16x8 {
    return *(const bf16x8*)(slot + (rbase + lq) * 32 + scp8);
  };

  floatx4 acc[8][4] = {};

  // ---- prologue: tile0 (kh0,kh1) + tile1 kh0 = 12 loads ----
  STAGE(Ag, Al[0][0], 0);
  STAGE(Bg, Bl[0][0], 0);
  STAGE(Ag, Al[0][1], 32);
  STAGE(Bg, Bl[0][1], 32);
  STAGE(Ag, Al[1][0], 64);
  STAGE(Bg, Bl[1][0], 64);
  asm volatile("s_waitcnt vmcnt(8)" ::: "memory");  // tile0 kh0 landed
  SCHED0;
  __builtin_amdgcn_s_barrier();
  SCHED0;

  int buf = 0;
  for (int kt = 0; kt < NT; ++kt) {
    const int nb = buf ^ 1;
    const int k1 = ((kt + 1 < NT) ? kt + 1 : NT - 1) << 6;  // clamped stream
    const int k2 = ((kt + 2 < NT) ? kt + 2 : NT - 1) << 6;
    bf16x8 af[8], bfr[4];

    // ==== phase A: kh0, full quadrant-pair; stage kh1(kt+1) ====
#pragma unroll
    for (int ni = 0; ni < 4; ni++) bfr[ni] = RD(Bl[buf][0], wc * 64 + ni * 16);
#pragma unroll
    for (int mi = 0; mi < 8; mi++) af[mi] = RD(Al[buf][0], wr * 128 + mi * 16);
    STAGE(Ag, Al[nb][1], k1 + 32);
    STAGE(Bg, Bl[nb][1], k1 + 32);
    SCHED0; __builtin_amdgcn_s_barrier(); SCHED0;
    __builtin_amdgcn_s_setprio(1);
#pragma unroll
    for (int mi = 0; mi < 8; mi++)
#pragma unroll
      for (int ni = 0; ni < 4; ni++)
        acc[mi][ni] = mfma16(af[mi], bfr[ni], acc[mi][ni]);
    __builtin_amdgcn_s_setprio(0);
    asm volatile("s_waitcnt vmcnt(8)" ::: "memory");
    SCHED0; __builtin_amdgcn_s_barrier(); SCHED0;

    // ==== phase B: kh1; stage kh0(kt+2) into CURRENT buf ====
#pragma unroll
    for (int ni = 0; ni < 4; ni++) bfr[ni] = RD(Bl[buf][1], wc * 64 + ni * 16);
#pragma unroll
    for (int mi = 0; mi < 8; mi++) af[mi] = RD(Al[buf][1], wr * 128 + mi * 16);
    STAGE(Ag, Al[buf][0], k2);
    STAGE(Bg, Bl[buf][0], k2);
    SCHED0; __builtin_amdgcn_s_barrier(); SCHED0;
    __builtin_amdgcn_s_setprio(1);
#pragma unroll
    for (int mi = 0; mi < 8; mi++)
#pragma unroll
      for (int ni = 0; ni < 4; ni++)
        acc[mi][ni] = mfma16(af[mi], bfr[ni], acc[mi][ni]);
    __builtin_amdgcn_s_setprio(0);
    asm volatile("s_waitcnt vmcnt(8)" ::: "memory");
    SCHED0; __builtin_amdgcn_s_barrier(); SCHED0;

    buf = nb;
  }
  asm volatile("s_waitcnt vmcnt(0)" ::: "memory");  // drain DMA before exit

  // ---- epilogue ----
  if (vt != nullptr && tn >= 16) {
    const int b = tm >> 2;
    const int sb = (tm & 3) * 256 + wr * 128 + lg * 4;
    const int head2 = (tn - 16) * 2;
#pragma unroll
    for (int ni = 0; ni < 4; ni++) {
      const int col = wc * 64 + ni * 16 + lq;
      bf16* vdst = vt + ((size_t)(b * NH + head2 + (col >> 7)) * DHD +
                         (col & 127)) * NSEQ + sb;
#pragma unroll
      for (int m = 0; m < 8; m++) {
        bf16x4 o;
#pragma unroll
        for (int r = 0; r < 4; r++) o[r] = (bf16)acc[m][ni][r];
        *(bf16x4*)(vdst + m * 16) = o;
      }
    }
  } else {
#pragma unroll
    for (int ni = 0; ni < 4; ni++) {
      const int col = tn * 256 + wc * 64 + ni * 16 + lq;
      const float bv = bias ? bias[col] : 0.f;
#pragma unroll
      for (int m = 0; m < 8; m++) {
        const size_t rb = (size_t)(tm * 256 + wr * 128 + m * 16 + lg * 4);
#pragma unroll
        for (int r = 0; r < 4; r++)
          C[(rb + r) * N + col] = (OutT)(acc[m][ni][r] + bv);
      }
    }
  }
}

// ---------------- GEMM: C[M,N] = A[M,K] * B[N,K]^T (+bias), OutT out ------
// 128x128 tile, BK=32, 4 waves (each 64x64), m97 structure. (out-proj)
template <typename OutT>
__global__ __launch_bounds__(256) void gemm_bt_kernel(
    const bf16* __restrict__ A, const bf16* __restrict__ B,
    OutT* __restrict__ C, const float* __restrict__ bias,
    int N, int K) {
  __shared__ bf16 As[128 * 32];
  __shared__ bf16 Bs[128 * 32];
  const int ntn = N >> 7;
  const int tm = blockIdx.x / ntn;
  const int tn = blockIdx.x - tm * ntn;
  const int tid = threadIdx.x;
  const int w = tid >> 6;
  const int lane = tid & 63;
  const int lq = lane & 15;
  const int lg = lane >> 4;
  const int wr = w >> 1;
  const int wc = w & 1;

  const bf16* Ag = A + (size_t)(tm * 128) * K;
  const bf16* Bg = B + (size_t)(tn * 128) * K;
  const int c0 = tid, c1 = tid + 256;
  const int r0 = c0 >> 2, o0 = (c0 & 3) * 8;
  const int r1 = c1 >> 2, o1 = (c1 & 3) * 8;
  bf16* lA0 = As + w * 512;
  bf16* lA1 = As + w * 512 + 2048;
  bf16* lB0 = Bs + w * 512;
  bf16* lB1 = Bs + w * 512 + 2048;

  floatx4 acc[4][4] = {};

  for (int k0 = 0; k0 < K; k0 += 32) {
    load_lds16(Ag + (size_t)r0 * K + k0 + o0, lA0);
    load_lds16(Ag + (size_t)r1 * K + k0 + o1, lA1);
    load_lds16(Bg + (size_t)r0 * K + k0 + o0, lB0);
    load_lds16(Bg + (size_t)r1 * K + k0 + o1, lB1);
    __syncthreads();
    bf16x8 af[4], bfr[4];
#pragma unroll
    for (int m = 0; m < 4; m++)
      af[m] = *(const bf16x8*)(As + (wr * 64 + m * 16 + lq) * 32 + lg * 8);
#pragma unroll
    for (int n = 0; n < 4; n++)
      bfr[n] = *(const bf16x8*)(Bs + (wc * 64 + n * 16 + lq) * 32 + lg * 8);
#pragma unroll
    for (int m = 0; m < 4; m++)
#pragma unroll
      for (int n = 0; n < 4; n++)
        acc[m][n] = mfma16(af[m], bfr[n], acc[m][n]);
    __syncthreads();
  }

#pragma unroll
  for (int n = 0; n < 4; n++) {
    const int ccol = tn * 128 + wc * 64 + n * 16 + lq;
    const float bv = bias ? bias[ccol] : 0.f;
#pragma unroll
    for (int m = 0; m < 4; m++) {
      const size_t rbase = (size_t)(tm * 128 + wr * 64 + m * 16 + lg * 4);
#pragma unroll
      for (int r = 0; r < 4; r++)
        C[(rbase + r) * N + ccol] = (OutT)(acc[m][n][r] + bv);
    }
  }
}

// ------ flash attention, 2 q-tiles per block (staging amortized 2x) -------
// grid 512 = (b:4, h:16, qpair:8); block handles q-tiles qp and qp+8.
// 4 waves, 16 q-rows each per group, KB=64, K/V LDS-staged double-buffered.
// T5 setprio, T13 defer-max, T1 XCD-chunked bid (512 = 8*64 -> each XCD
// 8 whole (b,h) groups = 4 MB L2). 2 blocks/CU, grid = exactly 1 round.
__global__ __launch_bounds__(256) void attn_kernel(
    const bf16* __restrict__ qkv, const bf16* __restrict__ vt,
    const int* __restrict__ ids, bf16* __restrict__ ao) {
  __shared__ bf16 Ksh[2][64 * 128];
  __shared__ bf16 Vsh[2][128 * 64];
  __shared__ bf16 plds[4][16][72];   // per-wave P buffer (rows 144B)
  const int bid = (blockIdx.x & 7) * 64 + (blockIdx.x >> 3);  // XCD chunked
  const int qp = bid & 7;
  const int h = (bid >> 3) & 15;
  const int b = bid >> 7;
  const int tid = threadIdx.x;
  const int w = tid >> 6;
  const int lane = tid & 63;
  const int lq = lane & 15;
  const int lg = lane >> 4;
  const int swz = (lq & 7) << 4;     // read-side XOR (bytes)

  // staging geometry (per wave: 4 K-instrs of 4 rows, 4 V-instrs of 8 rows)
  const int krow0 = w * 16 + (lane >> 4);   // + i*4
  const int kc = lane & 15;
  const int vrow0 = w * 32 + (lane >> 3);   // + i*8
  const int vc = lane & 7;
  const int vr7 = (lane >> 3) & 7;          // (vrow & 7), constant per lane

  const bf16* kg = qkv + DM + h * DHD;      // K plane base
  const bf16* vg = vt + (size_t)(b * NH + h) * DHD * NSEQ;

  auto stage = [&](int buf, int k0) {
#pragma unroll
    for (int i = 0; i < 4; i++) {
      const int kr = krow0 + i * 4;
      load_lds16(kg + (size_t)(b * NSEQ + k0 + kr) * E3 + ((kc ^ (kr & 7)) * 8),
                 &Ksh[buf][(w * 16 + i * 4) * 128]);
    }
#pragma unroll
    for (int i = 0; i < 4; i++) {
      const int vr = vrow0 + i * 8;
      load_lds16(vg + (size_t)vr * NSEQ + k0 + ((vc ^ vr7) * 8),
                 &Vsh[buf][(w * 32 + i * 8) * 64]);
    }
  };

  // Q fragments for both groups: Q[q=lq][dh = kk*32 + lg*8 + j]
  bf16x8 qf[2][4];
#pragma unroll
  for (int g = 0; g < 2; g++) {
    const int q0 = (qp + g * 8) * 64 + w * 16;
    const bf16* qb = qkv + (size_t)(b * NSEQ + q0 + lq) * E3 + h * DHD + lg * 8;
#pragma unroll
    for (int kk = 0; kk < 4; kk++) qf[g][kk] = *(const bf16x8*)(qb + kk * 32);
  }

  floatx4 acc[2][8] = {};
  float M[2][4], L[2][4];
#pragma unroll
  for (int g = 0; g < 2; g++)
#pragma unroll
    for (int r = 0; r < 4; r++) { M[g][r] = NEG_HUGE; L[g][r] = 0.f; }

  bf16 (*pw)[72] = plds[w];
  const int* idb = ids + b * NSEQ;

  stage(0, 0);
  __syncthreads();           // barrier drain includes vmcnt(0)
  int cur = 0;

  for (int t = 0; t < 16; t++) {
    const int k0 = t * 64;
    if (t < 15) stage(cur ^ 1, k0 + 64);   // prefetch next tile

    const bf16* Kc = Ksh[cur];
    const bf16* Vc = Vsh[cur];
#pragma unroll
    for (int g = 0; g < 2; g++) {
      // QK^T: S[q = lg*4+r][key = n*16 + lq]
      floatx4 s[4] = {};
      __builtin_amdgcn_s_setprio(1);
#pragma unroll
      for (int n = 0; n < 4; n++) {
        const int krow = n * 16 + lq;
#pragma unroll
        for (int kk = 0; kk < 4; kk++) {
          bf16x8 kf = *(const bf16x8*)(Kc + krow * 128 +
                                       (((kk * 64 + lg * 16) ^ swz) >> 1));
          s[n] = mfma16(qf[g][kk], kf, s[n]);
        }
      }
      __builtin_amdgcn_s_setprio(0);
      // bias (pre-scale, as in reference) + scale, row max
      float sa[4][4], pm[4];
#pragma unroll
      for (int r = 0; r < 4; r++) pm[r] = NEG_HUGE;
#pragma unroll
      for (int n = 0; n < 4; n++) {
        const float bv = idb[k0 + n * 16 + lq] ? MBIAS_S : 0.f;
#pragma unroll
        for (int r = 0; r < 4; r++) {
          sa[n][r] = s[n][r] * SCALE_F + bv;
          pm[r] = fmaxf(pm[r], sa[n][r]);
        }
      }
#pragma unroll
      for (int m = 1; m <= 8; m <<= 1)
#pragma unroll
        for (int r = 0; r < 4; r++)
          pm[r] = fmaxf(pm[r], __shfl_xor(pm[r], m, 64));

      // T13 defer-max
      int grew = 0;
#pragma unroll
      for (int r = 0; r < 4; r++)
        grew |= (pm[r] > M[g][r] + DEFER_THR) ? 1 : 0;
      const bool full = __any(grew);     // wave-uniform
      float corr[4];
      if (full) {
#pragma unroll
        for (int r = 0; r < 4; r++) {
          const float mn = fmaxf(M[g][r], pm[r]);
          corr[r] = __expf(M[g][r] - mn);
          M[g][r] = mn;
        }
      }
      float rs[4] = {0.f, 0.f, 0.f, 0.f};
#pragma unroll
      for (int n = 0; n < 4; n++)
#pragma unroll
        for (int r = 0; r < 4; r++) {
          const float p = __expf(sa[n][r] - M[g][r]);   // bounded by e^THR
          sa[n][r] = p;
          rs[r] += p;
        }
#pragma unroll
      for (int m = 1; m <= 8; m <<= 1)
#pragma unroll
        for (int r = 0; r < 4; r++) rs[r] += __shfl_xor(rs[r], m, 64);
      if (full) {
#pragma unroll
        for (int r = 0; r < 4; r++) L[g][r] = L[g][r] * corr[r] + rs[r];
#pragma unroll
        for (int n8 = 0; n8 < 8; n8++)
#pragma unroll
          for (int r = 0; r < 4; r++) acc[g][n8][r] *= corr[r];
      } else {
#pragma unroll
        for (int r = 0; r < 4; r++) L[g][r] += rs[r];
      }
      // P -> LDS (per-wave buffer; same-wave DS ops are ordered, so the
      // g=1 overwrite is safe after g=0's pf reads issued in order)
#pragma unroll
      for (int n = 0; n < 4; n++)
#pragma unroll
        for (int r = 0; r < 4; r++)
          pw[lg * 4 + r][n * 16 + lq] = (bf16)sa[n][r];
      bf16x8 pf0 = *(const bf16x8*)(&pw[lq][lg * 8]);
      bf16x8 pf1 = *(const bf16x8*)(&pw[lq][32 + lg * 8]);
      // PV from swizzled V tile [128][64]
      __builtin_amdgcn_s_setprio(1);
#pragma unroll
      for (int n8 = 0; n8 < 8; n8++) {
        const int vrow = n8 * 16 + lq;
        bf16x8 v0 = *(const bf16x8*)(Vc + vrow * 64 + (((lg * 16) ^ swz) >> 1));
        bf16x8 v1 = *(const bf16x8*)(Vc + vrow * 64 +
                                     (((64 + lg * 16) ^ swz) >> 1));
        acc[g][n8] = mfma16(pf0, v0, acc[g][n8]);
        acc[g][n8] = mfma16(pf1, v1, acc[g][n8]);
      }
      __builtin_amdgcn_s_setprio(0);
    }
    __syncthreads();         // publishes staged next tile; frees cur
    cur ^= 1;
  }

#pragma unroll
  for (int g = 0; g < 2; g++) {
    float inv[4];
#pragma unroll
    for (int r = 0; r < 4; r++) inv[r] = 1.f / L[g][r];
    const int q0 = (qp + g * 8) * 64 + w * 16;
    bf16* aob = ao + (size_t)(b * NSEQ + q0 + lg * 4) * DM + h * DHD + lq;
#pragma unroll
    for (int n8 = 0; n8 < 8; n8++)
#pragma unroll
      for (int r = 0; r < 4; r++)
        aob[(size_t)r * DM + n8 * 16] = (bf16)(acc[g][n8][r] * inv[r]);
  }
}

extern "C" void kernel_launch(void* const* d_in, const int* in_sizes, int n_in,
                              void* d_out, int out_size, void* d_ws, size_t ws_size,
                              hipStream_t stream) {
  const float* x     = (const float*)d_in[0];
  const int*   ids   = (const int*)d_in[1];
  const float* w_in  = (const float*)d_in[2];
  const float* w_out = (const float*)d_in[3];
  const float* b_out = (const float*)d_in[4];
  float* out = (float*)d_out;   // reference output dtype is float32

  // workspace layout (bf16 elements), total 128 MB
  bf16* ws  = (bf16*)d_ws;
  bf16* xb  = ws;                                   //  4096*2048
  bf16* wib = xb  + (size_t)4096 * 2048;            //  6144*2048
  bf16* wob = wib + (size_t)6144 * 2048;            //  2048*2048
  bf16* qkv = wob + (size_t)2048 * 2048;            //  4096*6144
  bf16* vtb = qkv + (size_t)4096 * 6144;            //  4*16*128*1024
  bf16* aob = vtb + (size_t)4 * 16 * 128 * 1024;    //  4096*2048

  cast3_kernel<<<24576, 256, 0, stream>>>(x, w_in, w_out, xb, wib, wob);
  // qkv[s, e] = x[s,:] . w_in[e,:]  — 256² merged-2-phase, fused V-transpose
  gemm256_bt_kernel<bf16><<<16 * 24, 512, 0, stream>>>(xb, wib, qkv, nullptr,
                                                       6144, 2048, vtb);
  attn_kernel<<<512, 256, 0, stream>>>(qkv, vtb, ids, aob);
  // out[s, e] = ao[s,:] . w_out[e,:] + b_out[e]
  gemm_bt_kernel<float><<<32 * 16, 256, 0, stream>>>(aob, wob, out, b_out, 2048, 2048);
}

// Round 16
// 292.078 us; speedup vs baseline: 1.0877x; 1.0877x over previous
//
#include <hip/hip_runtime.h>
#include <hip/hip_bf16.h>
#include <stdint.h>

typedef __bf16 bf16;
typedef __bf16 bf16x8 __attribute__((ext_vector_type(8)));
typedef __bf16 bf16x4 __attribute__((ext_vector_type(4)));
typedef float floatx4 __attribute__((ext_vector_type(4)));

#define NSEQ   1024
#define DM     2048
#define NH     16
#define DHD    128
#define E3     6144
#define SCALE_F 0.08838834764831845f
#define MBIAS_S (-1.0e9f * SCALE_F)
#define NEG_HUGE (-3.0e38f)
#define DEFER_THR 8.0f

static __device__ __forceinline__ floatx4 mfma16(bf16x8 a, bf16x8 b, floatx4 c) {
  return __builtin_amdgcn_mfma_f32_16x16x32_bf16(a, b, c, 0, 0, 0);
}

// global -> LDS direct copy, 16B per lane. LDS dest is wave-uniform base;
// HW adds lane*16.
static __device__ __forceinline__ void load_lds16(const bf16* g, bf16* l) {
  __builtin_amdgcn_global_load_lds(
      (__attribute__((address_space(1))) const void*)g,
      (__attribute__((address_space(3))) void*)l, 16, 0, 0);
}

#define SCHED0 __builtin_amdgcn_sched_barrier(0)

// ------- fused cast f32 -> bf16 for x, w_in, w_out (one dispatch) ---------
__global__ __launch_bounds__(256) void cast3_kernel(
    const float* __restrict__ x, const float* __restrict__ wi,
    const float* __restrict__ wo, bf16* __restrict__ xb,
    bf16* __restrict__ wib, bf16* __restrict__ wob) {
  const int blk = blockIdx.x;
  const float* src;
  bf16* dst;
  int base;
  if (blk < 8192)       { src = x;  dst = xb;  base = blk; }
  else if (blk < 20480) { src = wi; dst = wib; base = blk - 8192; }
  else                  { src = wo; dst = wob; base = blk - 20480; }
  const int i = base * 256 + threadIdx.x;
  float4 v = ((const float4*)src)[i];
  bf16x4 o;
  o[0] = (bf16)v.x; o[1] = (bf16)v.y; o[2] = (bf16)v.z; o[3] = (bf16)v.w;
  ((bf16x4*)dst)[i] = o;
}

// ======== 256x256 GEMM, 2 merged phases per K-tile (32 MFMA/region) =======
// C[M,N] = A[M,K]*B[N,K]^T (+bias). 512 thr = 8 waves (2M x 4N), BK=64 in
// two kh slots; LDS [2][2][256][32], colpair^=(row>>1)&3 swizzle. Counted
// vmcnt(8); never vmcnt(0) in loop. NO blockIdx chunking (r13: chunking
// doubled FETCH). Fused V-transpose epilogue (r14 verified: -8 us): for
// tn >= 16 write vt[b,h,dh,s] directly (acc fragment holds 4 consecutive
// s -> bf16x4 store), skip the dead qkv V-region C-write.
template <typename OutT>
__global__ __launch_bounds__(512) void gemm256_bt_kernel(
    const bf16* __restrict__ A, const bf16* __restrict__ B,
    OutT* __restrict__ C, const float* __restrict__ bias,
    int N, int K, bf16* __restrict__ vt) {
  __shared__ __align__(16) bf16 Al[2][2][256 * 32];
  __shared__ __align__(16) bf16 Bl[2][2][256 * 32];
  const int NT = K >> 6;
  const int ntn = N >> 8;
  const int tm = blockIdx.x / ntn;
  const int tn = blockIdx.x - tm * ntn;
  const int tid = threadIdx.x;
  const int w = tid >> 6, lane = tid & 63;
  const int lq = lane & 15, lg = lane >> 4;
  const int wr = w >> 2, wc = w & 3;
  const int sub = lane >> 2;                       // staging row-in-chunk
  const int cpl = (lane & 3) ^ ((lane >> 3) & 3);  // pre-swizzled src colpair
  const int scp8 = (lg ^ ((lq >> 1) & 3)) << 3;    // swizzled read col (elems)

  const bf16* Ag = A + (size_t)(tm * 256) * K;
  const bf16* Bg = B + (size_t)(tn * 256) * K;

  auto STAGE = [&](const bf16* G, bf16* Ldst, int kcol) {
#pragma unroll
    for (int j = 0; j < 2; j++) {
      const int r0 = w * 32 + j * 16;
      load_lds16(G + (size_t)(r0 + sub) * K + kcol + cpl * 8, Ldst + r0 * 32);
    }
  };
  auto RD = [&](const bf16* slot, int rbase) -> bf16x8 {
    return *(const bf16x8*)(slot + (rbase + lq) * 32 + scp8);
  };

  floatx4 acc[8][4] = {};

  // ---- prologue: tile0 (kh0,kh1) + tile1 kh0 = 12 loads ----
  STAGE(Ag, Al[0][0], 0);
  STAGE(Bg, Bl[0][0], 0);
  STAGE(Ag, Al[0][1], 32);
  STAGE(Bg, Bl[0][1], 32);
  STAGE(Ag, Al[1][0], 64);
  STAGE(Bg, Bl[1][0], 64);
  asm volatile("s_waitcnt vmcnt(8)" ::: "memory");  // tile0 kh0 landed
  SCHED0;
  __builtin_amdgcn_s_barrier();
  SCHED0;

  int buf = 0;
  for (int kt = 0; kt < NT; ++kt) {
    const int nb = buf ^ 1;
    const int k1 = ((kt + 1 < NT) ? kt + 1 : NT - 1) << 6;  // clamped stream
    const int k2 = ((kt + 2 < NT) ? kt + 2 : NT - 1) << 6;
    bf16x8 af[8], bfr[4];

    // ==== phase A: kh0, full quadrant-pair; stage kh1(kt+1) ====
#pragma unroll
    for (int ni = 0; ni < 4; ni++) bfr[ni] = RD(Bl[buf][0], wc * 64 + ni * 16);
#pragma unroll
    for (int mi = 0; mi < 8; mi++) af[mi] = RD(Al[buf][0], wr * 128 + mi * 16);
    STAGE(Ag, Al[nb][1], k1 + 32);
    STAGE(Bg, Bl[nb][1], k1 + 32);
    SCHED0; __builtin_amdgcn_s_barrier(); SCHED0;
    __builtin_amdgcn_s_setprio(1);
#pragma unroll
    for (int mi = 0; mi < 8; mi++)
#pragma unroll
      for (int ni = 0; ni < 4; ni++)
        acc[mi][ni] = mfma16(af[mi], bfr[ni], acc[mi][ni]);
    __builtin_amdgcn_s_setprio(0);
    asm volatile("s_waitcnt vmcnt(8)" ::: "memory");
    SCHED0; __builtin_amdgcn_s_barrier(); SCHED0;

    // ==== phase B: kh1; stage kh0(kt+2) into CURRENT buf ====
#pragma unroll
    for (int ni = 0; ni < 4; ni++) bfr[ni] = RD(Bl[buf][1], wc * 64 + ni * 16);
#pragma unroll
    for (int mi = 0; mi < 8; mi++) af[mi] = RD(Al[buf][1], wr * 128 + mi * 16);
    STAGE(Ag, Al[buf][0], k2);
    STAGE(Bg, Bl[buf][0], k2);
    SCHED0; __builtin_amdgcn_s_barrier(); SCHED0;
    __builtin_amdgcn_s_setprio(1);
#pragma unroll
    for (int mi = 0; mi < 8; mi++)
#pragma unroll
      for (int ni = 0; ni < 4; ni++)
        acc[mi][ni] = mfma16(af[mi], bfr[ni], acc[mi][ni]);
    __builtin_amdgcn_s_setprio(0);
    asm volatile("s_waitcnt vmcnt(8)" ::: "memory");
    SCHED0; __builtin_amdgcn_s_barrier(); SCHED0;

    buf = nb;
  }
  asm volatile("s_waitcnt vmcnt(0)" ::: "memory");  // drain DMA before exit

  // ---- epilogue ----
  if (vt != nullptr && tn >= 16) {
    const int b = tm >> 2;
    const int sb = (tm & 3) * 256 + wr * 128 + lg * 4;
    const int head2 = (tn - 16) * 2;
#pragma unroll
    for (int ni = 0; ni < 4; ni++) {
      const int col = wc * 64 + ni * 16 + lq;
      bf16* vdst = vt + ((size_t)(b * NH + head2 + (col >> 7)) * DHD +
                         (col & 127)) * NSEQ + sb;
#pragma unroll
      for (int m = 0; m < 8; m++) {
        bf16x4 o;
#pragma unroll
        for (int r = 0; r < 4; r++) o[r] = (bf16)acc[m][ni][r];
        *(bf16x4*)(vdst + m * 16) = o;
      }
    }
  } else {
#pragma unroll
    for (int ni = 0; ni < 4; ni++) {
      const int col = tn * 256 + wc * 64 + ni * 16 + lq;
      const float bv = bias ? bias[col] : 0.f;
#pragma unroll
      for (int m = 0; m < 8; m++) {
        const size_t rb = (size_t)(tm * 256 + wr * 128 + m * 16 + lg * 4);
#pragma unroll
        for (int r = 0; r < 4; r++)
          C[(rb + r) * N + col] = (OutT)(acc[m][ni][r] + bv);
      }
    }
  }
}

// ---------------- GEMM: C[M,N] = A[M,K] * B[N,K]^T (+bias), OutT out ------
// 128x128 tile, BK=32, 4 waves (each 64x64), m97 structure. (out-proj)
template <typename OutT>
__global__ __launch_bounds__(256) void gemm_bt_kernel(
    const bf16* __restrict__ A, const bf16* __restrict__ B,
    OutT* __restrict__ C, const float* __restrict__ bias,
    int N, int K) {
  __shared__ bf16 As[128 * 32];
  __shared__ bf16 Bs[128 * 32];
  const int ntn = N >> 7;
  const int tm = blockIdx.x / ntn;
  const int tn = blockIdx.x - tm * ntn;
  const int tid = threadIdx.x;
  const int w = tid >> 6;
  const int lane = tid & 63;
  const int lq = lane & 15;
  const int lg = lane >> 4;
  const int wr = w >> 1;
  const int wc = w & 1;

  const bf16* Ag = A + (size_t)(tm * 128) * K;
  const bf16* Bg = B + (size_t)(tn * 128) * K;
  const int c0 = tid, c1 = tid + 256;
  const int r0 = c0 >> 2, o0 = (c0 & 3) * 8;
  const int r1 = c1 >> 2, o1 = (c1 & 3) * 8;
  bf16* lA0 = As + w * 512;
  bf16* lA1 = As + w * 512 + 2048;
  bf16* lB0 = Bs + w * 512;
  bf16* lB1 = Bs + w * 512 + 2048;

  floatx4 acc[4][4] = {};

  for (int k0 = 0; k0 < K; k0 += 32) {
    load_lds16(Ag + (size_t)r0 * K + k0 + o0, lA0);
    load_lds16(Ag + (size_t)r1 * K + k0 + o1, lA1);
    load_lds16(Bg + (size_t)r0 * K + k0 + o0, lB0);
    load_lds16(Bg + (size_t)r1 * K + k0 + o1, lB1);
    __syncthreads();
    bf16x8 af[4], bfr[4];
#pragma unroll
    for (int m = 0; m < 4; m++)
      af[m] = *(const bf16x8*)(As + (wr * 64 + m * 16 + lq) * 32 + lg * 8);
#pragma unroll
    for (int n = 0; n < 4; n++)
      bfr[n] = *(const bf16x8*)(Bs + (wc * 64 + n * 16 + lq) * 32 + lg * 8);
#pragma unroll
    for (int m = 0; m < 4; m++)
#pragma unroll
      for (int n = 0; n < 4; n++)
        acc[m][n] = mfma16(af[m], bfr[n], acc[m][n]);
    __syncthreads();
  }

#pragma unroll
  for (int n = 0; n < 4; n++) {
    const int ccol = tn * 128 + wc * 64 + n * 16 + lq;
    const float bv = bias ? bias[ccol] : 0.f;
#pragma unroll
    for (int m = 0; m < 4; m++) {
      const size_t rbase = (size_t)(tm * 128 + wr * 64 + m * 16 + lg * 4);
#pragma unroll
      for (int r = 0; r < 4; r++)
        C[(rbase + r) * N + ccol] = (OutT)(acc[m][n][r] + bv);
    }
  }
}

// ---------------- flash attention, LDS-staged K/V (double-buffered) --------
// grid 1024 = (b:4, h:16, qtile:16). 4 waves, 16 q-rows each, KB=64.
// T5 setprio, T13 defer-max (THR=8). T1 XCD-chunked blockIdx swizzle
// (round-11 A/B-verified: ~65 vs ~74 us). V staged in LDS (V-direct
// regressed 3x in r12; 2-qtile amortization regressed in r15).
__global__ __launch_bounds__(256) void attn_kernel(
    const bf16* __restrict__ qkv, const bf16* __restrict__ vt,
    const int* __restrict__ ids, bf16* __restrict__ ao) {
  __shared__ bf16 Ksh[2][64 * 128];
  __shared__ bf16 Vsh[2][128 * 64];
  __shared__ bf16 plds[4][16][72];   // per-wave P buffer (rows 144B, 16B-mult)
  const int bid = (blockIdx.x & 7) * 128 + (blockIdx.x >> 3);  // XCD chunked
  const int qt = bid & 15;
  const int h = (bid >> 4) & 15;
  const int b = bid >> 8;
  const int tid = threadIdx.x;
  const int w = tid >> 6;
  const int lane = tid & 63;
  const int lq = lane & 15;
  const int lg = lane >> 4;
  const int q0 = qt * 64 + w * 16;
  const int swz = (lq & 7) << 4;     // read-side XOR (bytes)

  // staging geometry (per wave: 4 K-instrs of 4 rows, 4 V-instrs of 8 rows)
  const int krow0 = w * 16 + (lane >> 4);   // + i*4
  const int kc = lane & 15;
  const int vrow0 = w * 32 + (lane >> 3);   // + i*8
  const int vc = lane & 7;
  const int vr7 = (lane >> 3) & 7;          // (vrow & 7), constant per lane

  const bf16* kg = qkv + DM + h * DHD;      // K plane base
  const bf16* vg = vt + (size_t)(b * NH + h) * DHD * NSEQ;

  auto stage = [&](int buf, int k0) {
#pragma unroll
    for (int i = 0; i < 4; i++) {
      const int kr = krow0 + i * 4;
      load_lds16(kg + (size_t)(b * NSEQ + k0 + kr) * E3 + ((kc ^ (kr & 7)) * 8),
                 &Ksh[buf][(w * 16 + i * 4) * 128]);
    }
#pragma unroll
    for (int i = 0; i < 4; i++) {
      const int vr = vrow0 + i * 8;
      load_lds16(vg + (size_t)vr * NSEQ + k0 + ((vc ^ vr7) * 8),
                 &Vsh[buf][(w * 32 + i * 8) * 64]);
    }
  };

  // Q fragments hoisted: Q[q=lq][dh = kk*32 + lg*8 + j]
  bf16x8 qf[4];
  const bf16* qb = qkv + (size_t)(b * NSEQ + q0 + lq) * E3 + h * DHD + lg * 8;
#pragma unroll
  for (int kk = 0; kk < 4; kk++) qf[kk] = *(const bf16x8*)(qb + kk * 32);

  floatx4 acc[8] = {};
  float M[4], L[4];
#pragma unroll
  for (int r = 0; r < 4; r++) { M[r] = NEG_HUGE; L[r] = 0.f; }

  bf16 (*pw)[72] = plds[w];
  const int* idb = ids + b * NSEQ;

  stage(0, 0);
  __syncthreads();           // barrier drain includes vmcnt(0)
  int cur = 0;

  for (int t = 0; t < 16; t++) {
    const int k0 = t * 64;
    if (t < 15) stage(cur ^ 1, k0 + 64);   // prefetch next tile

    // QK^T: S[q = lg*4+r][key = n*16 + lq]
    const bf16* Kc = Ksh[cur];
    floatx4 s[4] = {};
    __builtin_amdgcn_s_setprio(1);
#pragma unroll
    for (int n = 0; n < 4; n++) {
      const int krow = n * 16 + lq;
#pragma unroll
      for (int kk = 0; kk < 4; kk++) {
        bf16x8 kf = *(const bf16x8*)(Kc + krow * 128 +
                                     (((kk * 64 + lg * 16) ^ swz) >> 1));
        s[n] = mfma16(qf[kk], kf, s[n]);
      }
    }
    __builtin_amdgcn_s_setprio(0);
    // bias (pre-scale, as in reference) + scale, row max
    float sa[4][4], pm[4];
#pragma unroll
    for (int r = 0; r < 4; r++) pm[r] = NEG_HUGE;
#pragma unroll
    for (int n = 0; n < 4; n++) {
      const float bv = idb[k0 + n * 16 + lq] ? MBIAS_S : 0.f;
#pragma unroll
      for (int r = 0; r < 4; r++) {
        sa[n][r] = s[n][r] * SCALE_F + bv;
        pm[r] = fmaxf(pm[r], sa[n][r]);
      }
    }
#pragma unroll
    for (int m = 1; m <= 8; m <<= 1)
#pragma unroll
      for (int r = 0; r < 4; r++) pm[r] = fmaxf(pm[r], __shfl_xor(pm[r], m, 64));

    // T13 defer-max: skip rescale when no row grew its max by > THR.
    int grew = 0;
#pragma unroll
    for (int r = 0; r < 4; r++) grew |= (pm[r] > M[r] + DEFER_THR) ? 1 : 0;
    const bool full = __any(grew);     // wave-uniform
    float corr[4];
    if (full) {
#pragma unroll
      for (int r = 0; r < 4; r++) {
        const float mn = fmaxf(M[r], pm[r]);
        corr[r] = __expf(M[r] - mn);
        M[r] = mn;
      }
    }
    float rs[4] = {0.f, 0.f, 0.f, 0.f};
#pragma unroll
    for (int n = 0; n < 4; n++)
#pragma unroll
      for (int r = 0; r < 4; r++) {
        const float p = __expf(sa[n][r] - M[r]);   // bounded by e^THR
        sa[n][r] = p;
        rs[r] += p;
      }
#pragma unroll
    for (int m = 1; m <= 8; m <<= 1)
#pragma unroll
      for (int r = 0; r < 4; r++) rs[r] += __shfl_xor(rs[r], m, 64);
    if (full) {
#pragma unroll
      for (int r = 0; r < 4; r++) L[r] = L[r] * corr[r] + rs[r];
#pragma unroll
      for (int n8 = 0; n8 < 8; n8++)
#pragma unroll
        for (int r = 0; r < 4; r++) acc[n8][r] *= corr[r];
    } else {
#pragma unroll
      for (int r = 0; r < 4; r++) L[r] += rs[r];
    }
    // P -> LDS (per-wave buffer; same-wave DS ops are ordered)
#pragma unroll
    for (int n = 0; n < 4; n++)
#pragma unroll
      for (int r = 0; r < 4; r++) pw[lg * 4 + r][n * 16 + lq] = (bf16)sa[n][r];
    // P A-fragments: P[q=lq][key = lg*8+j] and [32 + lg*8+j]
    bf16x8 pf0 = *(const bf16x8*)(&pw[lq][lg * 8]);
    bf16x8 pf1 = *(const bf16x8*)(&pw[lq][32 + lg * 8]);
    // PV from swizzled V tile [128][64]
    const bf16* Vc = Vsh[cur];
    __builtin_amdgcn_s_setprio(1);
#pragma unroll
    for (int n8 = 0; n8 < 8; n8++) {
      const int vrow = n8 * 16 + lq;
      bf16x8 v0 = *(const bf16x8*)(Vc + vrow * 64 + (((lg * 16) ^ swz) >> 1));
      bf16x8 v1 = *(const bf16x8*)(Vc + vrow * 64 + (((64 + lg * 16) ^ swz) >> 1));
      acc[n8] = mfma16(pf0, v0, acc[n8]);
      acc[n8] = mfma16(pf1, v1, acc[n8]);
    }
    __builtin_amdgcn_s_setprio(0);
    __syncthreads();         // publishes staged next tile; frees cur for reuse
    cur ^= 1;
  }

  float inv[4];
#pragma unroll
  for (int r = 0; r < 4; r++) inv[r] = 1.f / L[r];
  bf16* aob = ao + (size_t)(b * NSEQ + q0 + lg * 4) * DM + h * DHD + lq;
#pragma unroll
  for (int n8 = 0; n8 < 8; n8++)
#pragma unroll
    for (int r = 0; r < 4; r++)
      aob[(size_t)r * DM + n8 * 16] = (bf16)(acc[n8][r] * inv[r]);
}

extern "C" void kernel_launch(void* const* d_in, const int* in_sizes, int n_in,
                              void* d_out, int out_size, void* d_ws, size_t ws_size,
                              hipStream_t stream) {
  const float* x     = (const float*)d_in[0];
  const int*   ids   = (const int*)d_in[1];
  const float* w_in  = (const float*)d_in[2];
  const float* w_out = (const float*)d_in[3];
  const float* b_out = (const float*)d_in[4];
  float* out = (float*)d_out;   // reference output dtype is float32

  // workspace layout (bf16 elements), total 128 MB
  bf16* ws  = (bf16*)d_ws;
  bf16* xb  = ws;                                   //  4096*2048
  bf16* wib = xb  + (size_t)4096 * 2048;            //  6144*2048
  bf16* wob = wib + (size_t)6144 * 2048;            //  2048*2048
  bf16* qkv = wob + (size_t)2048 * 2048;            //  4096*6144
  bf16* vtb = qkv + (size_t)4096 * 6144;            //  4*16*128*1024
  bf16* aob = vtb + (size_t)4 * 16 * 128 * 1024;    //  4096*2048

  cast3_kernel<<<24576, 256, 0, stream>>>(x, w_in, w_out, xb, wib, wob);
  // qkv[s, e] = x[s,:] . w_in[e,:]  — 256² merged-2-phase, fused V-transpose
  gemm256_bt_kernel<bf16><<<16 * 24, 512, 0, stream>>>(xb, wib, qkv, nullptr,
                                                       6144, 2048, vtb);
  attn_kernel<<<1024, 256, 0, stream>>>(qkv, vtb, ids, aob);
  // out[s, e] = ao[s,:] . w_out[e,:] + b_out[e]
  gemm_bt_kernel<float><<<32 * 16, 256, 0, stream>>>(aob, wob, out, b_out, 2048, 2048);
}